// Round 1
// baseline (458.347 us; speedup 1.0000x reference)
//
#include <hip/hip_runtime.h>
#include <hip/hip_fp16.h>

typedef _Float16 half8 __attribute__((ext_vector_type(8)));
typedef float f32x4 __attribute__((ext_vector_type(4)));

#define B_   4
#define L_   4096
#define D_   128
#define M_   (B_*L_)     // 16384
#define D2_  256
#define H_   512
#define OUT_ 55

__device__ __forceinline__ f32x4 mfma16(half8 a, half8 b, f32x4 c) {
    return __builtin_amdgcn_mfma_f32_16x16x32_f16(a, b, c, 0, 0, 0);
}

// ---- weight swizzle offsets (in halfs) within wsw region ----
#define WQ_OFF   0
#define WV1_OFF  16384
#define WK_OFF   32768
#define WV2_OFF  49152
#define WP1_OFF  65536
#define WP2_OFF  81920
#define WF1_OFF  98304     // 256x512 = 131072
#define WF2_OFF  229376    // 512x256 = 131072
#define WO_OFF   360448    // 256x64 (padded) = 16384
#define WSW_TOTAL 376832

// Pre-swizzle weights (fp32 row-major [K][N]) into B-fragment layout fp16:
// addr = (((s*nc + c)*4 + q)*16 + ln)*8 + j ; s=k>>5,q=(k>>3)&3,j=k&7,c=n>>4,ln=n&15
__global__ void prep_kernel(const float* Wq, const float* Wv1, const float* Wk,
                            const float* Wv2, const float* Wp1, const float* Wp2,
                            const float* Wf1, const float* Wf2, const float* Wo,
                            _Float16* wsw) {
    int id = blockIdx.y;
    int t  = blockIdx.x * 256 + threadIdx.x;
    const float* src = nullptr; int K = 0, N = 0, Npad = 0, off = 0;
    switch (id) {
        case 0: src = Wq;  K = 128; N = 128; Npad = 128; off = WQ_OFF;  break;
        case 1: src = Wv1; K = 128; N = 128; Npad = 128; off = WV1_OFF; break;
        case 2: src = Wk;  K = 128; N = 128; Npad = 128; off = WK_OFF;  break;
        case 3: src = Wv2; K = 128; N = 128; Npad = 128; off = WV2_OFF; break;
        case 4: src = Wp1; K = 128; N = 128; Npad = 128; off = WP1_OFF; break;
        case 5: src = Wp2; K = 128; N = 128; Npad = 128; off = WP2_OFF; break;
        case 6: src = Wf1; K = 256; N = 512; Npad = 512; off = WF1_OFF; break;
        case 7: src = Wf2; K = 512; N = 256; Npad = 256; off = WF2_OFF; break;
        case 8: src = Wo;  K = 256; N = 55;  Npad = 64;  off = WO_OFF;  break;
        default: return;
    }
    int total = K * Npad;
    if (t >= total) return;
    int k = t / Npad, n = t % Npad;
    float v = (n < N) ? src[k * N + n] : 0.f;
    int s = k >> 5, q = (k >> 3) & 3, j = k & 7, c = n >> 4, ln = n & 15;
    int nc = Npad >> 4;
    wsw[off + (((s * nc + c) * 4 + q) * 16 + ln) * 8 + j] = (_Float16)v;
}

// LayerNorm over D=128, one wave per token, fp32 in -> fp16 out
__global__ __launch_bounds__(256) void ln_kernel(const float* x1, const float* x2,
        const float* g1, const float* b1, const float* g2, const float* b2,
        _Float16* x1n, _Float16* x2n) {
    int wave = threadIdx.x >> 6, lane = threadIdx.x & 63;
    int token = blockIdx.x * 4 + wave;
    const float* x = blockIdx.y ? x2 : x1;
    const float* g = blockIdx.y ? g2 : g1;
    const float* bb = blockIdx.y ? b2 : b1;
    _Float16* o = blockIdx.y ? x2n : x1n;
    const float* xr = x + (size_t)token * D_;
    float a0 = xr[lane], a1 = xr[lane + 64];
    float s = a0 + a1, s2 = a0 * a0 + a1 * a1;
    #pragma unroll
    for (int off = 1; off < 64; off <<= 1) {
        s += __shfl_xor(s, off);
        s2 += __shfl_xor(s2, off);
    }
    float mean = s * (1.f / 128.f);
    float var = s2 * (1.f / 128.f) - mean * mean;
    float inv = rsqrtf(var + 1e-5f);
    _Float16* orow = o + (size_t)token * D_;
    orow[lane]      = (_Float16)((a0 - mean) * inv * g[lane] + bb[lane]);
    orow[lane + 64] = (_Float16)((a1 - mean) * inv * g[lane + 64] + bb[lane + 64]);
}

// Projections: q1 = x1n@Wq+bq ; v1 = x1n@Wv1+bv1 ; k2 = x2n@Wk+bk ; v2 = x2n@Wv2+bv2
// v1/v2 stored in PV-B-fragment swizzled layout (per batch); q1/k2 row-major fp16.
__global__ __launch_bounds__(256) void proj_kernel(const _Float16* x1n, const _Float16* x2n,
        const _Float16* wsw, const float* bq, const float* bv1, const float* bk,
        const float* bv2, _Float16* q1, _Float16* k2, _Float16* v1sw, _Float16* v2sw) {
    int g = blockIdx.y;   // 0:Wq 1:Wv1 2:Wk 3:Wv2
    const _Float16* A = (g < 2) ? x1n : x2n;
    const _Float16* Bw = wsw + g * 16384;
    const float* bias = (g == 0) ? bq : (g == 1) ? bv1 : (g == 2) ? bk : bv2;
    int wave = threadIdx.x >> 6, lane = threadIdx.x & 63;
    int quad = lane >> 4, ln = lane & 15;
    int mbase = blockIdx.x * 64 + wave * 16;

    half8 a[4];
    const _Float16* Arow = A + (size_t)(mbase + ln) * D_ + quad * 8;
    #pragma unroll
    for (int s = 0; s < 4; s++) a[s] = *(const half8*)(Arow + s * 32);

    f32x4 acc[8];
    #pragma unroll
    for (int c = 0; c < 8; c++) {
        acc[c] = f32x4{0.f, 0.f, 0.f, 0.f};
        #pragma unroll
        for (int s = 0; s < 4; s++) {
            half8 bf = *(const half8*)(Bw + ((size_t)((s * 8 + c) * 64 + lane)) * 8);
            acc[c] = mfma16(a[s], bf, acc[c]);
        }
    }
    bool isV = (g == 1) || (g == 3);
    _Float16* out = (g == 0) ? q1 : (g == 2) ? k2 : (g == 1) ? v1sw : v2sw;
    #pragma unroll
    for (int c = 0; c < 8; c++) {
        int n = c * 16 + ln;
        float bv = bias[n];
        #pragma unroll
        for (int r = 0; r < 4; r++) {
            int m = mbase + quad * 4 + r;
            float val = acc[c][r] + bv;
            if (!isV) {
                out[(size_t)m * D_ + n] = (_Float16)val;
            } else {
                int b = m >> 12, l = m & (L_ - 1);
                int tt = l >> 5, q2 = (l >> 3) & 3, j = l & 7;
                out[(size_t)b * (L_ * D_) + (((tt * 8 + c) * 64 + q2 * 16 + ln) * 8 + j)]
                    = (_Float16)val;
            }
        }
    }
}

// Flash attention. Q := k2 rows (att row index), K := q1, dual V. 64 Q-rows/block.
__global__ __launch_bounds__(256) void flash_kernel(const _Float16* q1, const _Float16* k2,
        const _Float16* v1sw, const _Float16* v2sw, _Float16* att1, _Float16* att2) {
    int b = blockIdx.y;
    int wave = threadIdx.x >> 6, lane = threadIdx.x & 63;
    int quad = lane >> 4, ln = lane & 15;
    int abase = blockIdx.x * 64 + wave * 16;
    const _Float16* Q  = k2 + (size_t)b * L_ * D_;
    const _Float16* K  = q1 + (size_t)b * L_ * D_;
    const _Float16* V1 = v1sw + (size_t)b * L_ * D_;
    const _Float16* V2 = v2sw + (size_t)b * L_ * D_;

    __shared__ _Float16 pbuf[4][16 * 32];

    half8 qf[4];
    {
        const _Float16* Qrow = Q + (size_t)(abase + ln) * D_ + quad * 8;
        #pragma unroll
        for (int s = 0; s < 4; s++) qf[s] = *(const half8*)(Qrow + s * 32);
    }
    f32x4 o1[8], o2[8];
    #pragma unroll
    for (int c = 0; c < 8; c++) { o1[c] = f32x4{0,0,0,0}; o2[c] = f32x4{0,0,0,0}; }
    float mrow[4], lrow[4];
    #pragma unroll
    for (int r = 0; r < 4; r++) { mrow[r] = -1e30f; lrow[r] = 0.f; }
    const float scale = 0.08838834764831845f;   // 1/sqrt(128)

    for (int t = 0; t < L_ / 32; t++) {
        f32x4 sacc[2];
        sacc[0] = f32x4{0,0,0,0}; sacc[1] = f32x4{0,0,0,0};
        #pragma unroll
        for (int ch = 0; ch < 2; ch++) {
            const _Float16* Krow = K + (size_t)(t * 32 + ch * 16 + ln) * D_ + quad * 8;
            #pragma unroll
            for (int s = 0; s < 4; s++) {
                half8 kf = *(const half8*)(Krow + s * 32);
                sacc[ch] = mfma16(qf[s], kf, sacc[ch]);
            }
        }
        // online softmax (rows m = quad*4+r, cols ch*16+ln)
        float mt[4];
        #pragma unroll
        for (int r = 0; r < 4; r++) {
            float v0 = sacc[0][r] * scale, v1 = sacc[1][r] * scale;
            sacc[0][r] = v0; sacc[1][r] = v1;
            mt[r] = fmaxf(v0, v1);
        }
        #pragma unroll
        for (int off = 1; off < 16; off <<= 1) {
            #pragma unroll
            for (int r = 0; r < 4; r++) mt[r] = fmaxf(mt[r], __shfl_xor(mt[r], off));
        }
        float alpha[4], psum[4];
        #pragma unroll
        for (int r = 0; r < 4; r++) {
            float mnew = fmaxf(mrow[r], mt[r]);
            alpha[r] = __expf(mrow[r] - mnew);
            mrow[r] = mnew;
            float p0 = __expf(sacc[0][r] - mnew);
            float p1 = __expf(sacc[1][r] - mnew);
            sacc[0][r] = p0; sacc[1][r] = p1;
            psum[r] = p0 + p1;
        }
        #pragma unroll
        for (int off = 1; off < 16; off <<= 1) {
            #pragma unroll
            for (int r = 0; r < 4; r++) psum[r] += __shfl_xor(psum[r], off);
        }
        #pragma unroll
        for (int r = 0; r < 4; r++) lrow[r] = lrow[r] * alpha[r] + psum[r];

        // P (C-layout) -> LDS -> A-fragment layout
        _Float16* pb = pbuf[wave];
        #pragma unroll
        for (int ch = 0; ch < 2; ch++)
            #pragma unroll
            for (int r = 0; r < 4; r++)
                pb[(quad * 4 + r) * 32 + ch * 16 + ln] = (_Float16)sacc[ch][r];

        // rescale O
        #pragma unroll
        for (int c = 0; c < 8; c++)
            #pragma unroll
            for (int r = 0; r < 4; r++) { o1[c][r] *= alpha[r]; o2[c][r] *= alpha[r]; }

        half8 pf = *(const half8*)(pb + ln * 32 + quad * 8);
        #pragma unroll
        for (int c = 0; c < 8; c++) {
            half8 v1f = *(const half8*)(V1 + ((size_t)((t * 8 + c) * 64 + lane)) * 8);
            half8 v2f = *(const half8*)(V2 + ((size_t)((t * 8 + c) * 64 + lane)) * 8);
            o1[c] = mfma16(pf, v1f, o1[c]);
            o2[c] = mfma16(pf, v2f, o2[c]);
        }
    }
    #pragma unroll
    for (int c = 0; c < 8; c++)
        #pragma unroll
        for (int r = 0; r < 4; r++) {
            int tok = (b << 12) + abase + quad * 4 + r;
            int n = c * 16 + ln;
            float inv = 1.f / lrow[r];
            att1[(size_t)tok * D_ + n] = (_Float16)(o1[c][r] * inv);
            att2[(size_t)tok * D_ + n] = (_Float16)(o2[c][r] * inv);
        }
}

// out1 = att1@Wp1+bp1+x1 ; out2 = att2@Wp2+bp2+x2 ; concat -> res (fp32) ; LNf -> xn (fp16)
__global__ __launch_bounds__(256) void attn_out_kernel(const _Float16* att1, const _Float16* att2,
        const _Float16* wsw, const float* bp1, const float* bp2,
        const float* x1, const float* x2, const float* lnf_g, const float* lnf_b,
        float* res, _Float16* xn) {
    int wave = threadIdx.x >> 6, lane = threadIdx.x & 63;
    int quad = lane >> 4, ln = lane & 15;
    int mbase = blockIdx.x * 64 + wave * 16;
    const _Float16* Wp1 = wsw + WP1_OFF;
    const _Float16* Wp2 = wsw + WP2_OFF;

    half8 a1[4], a2[4];
    const _Float16* r1 = att1 + (size_t)(mbase + ln) * D_ + quad * 8;
    const _Float16* r2 = att2 + (size_t)(mbase + ln) * D_ + quad * 8;
    #pragma unroll
    for (int s = 0; s < 4; s++) { a1[s] = *(const half8*)(r1 + s * 32); a2[s] = *(const half8*)(r2 + s * 32); }

    f32x4 y1[8], y2[8];
    #pragma unroll
    for (int c = 0; c < 8; c++) {
        y1[c] = f32x4{0,0,0,0}; y2[c] = f32x4{0,0,0,0};
        #pragma unroll
        for (int s = 0; s < 4; s++) {
            y1[c] = mfma16(a1[s], *(const half8*)(Wp1 + ((size_t)((s * 8 + c) * 64 + lane)) * 8), y1[c]);
            y2[c] = mfma16(a2[s], *(const half8*)(Wp2 + ((size_t)((s * 8 + c) * 64 + lane)) * 8), y2[c]);
        }
    }
    // bias + residual
    #pragma unroll
    for (int c = 0; c < 8; c++) {
        int n = c * 16 + ln;
        float b1v = bp1[n], b2v = bp2[n];
        #pragma unroll
        for (int r = 0; r < 4; r++) {
            int m = mbase + quad * 4 + r;
            y1[c][r] += b1v + x1[(size_t)m * D_ + n];
            y2[c][r] += b2v + x2[(size_t)m * D_ + n];
        }
    }
    // LN over concat(256)
    float sum[4] = {0,0,0,0}, sq[4] = {0,0,0,0};
    #pragma unroll
    for (int c = 0; c < 8; c++)
        #pragma unroll
        for (int r = 0; r < 4; r++) {
            sum[r] += y1[c][r] + y2[c][r];
            sq[r]  += y1[c][r] * y1[c][r] + y2[c][r] * y2[c][r];
        }
    #pragma unroll
    for (int off = 1; off < 16; off <<= 1)
        #pragma unroll
        for (int r = 0; r < 4; r++) { sum[r] += __shfl_xor(sum[r], off); sq[r] += __shfl_xor(sq[r], off); }
    #pragma unroll
    for (int r = 0; r < 4; r++) {
        float mean = sum[r] * (1.f / 256.f);
        float var = sq[r] * (1.f / 256.f) - mean * mean;
        float inv = rsqrtf(var + 1e-5f);
        int m = mbase + quad * 4 + r;
        #pragma unroll
        for (int c = 0; c < 8; c++) {
            int n = c * 16 + ln;
            res[(size_t)m * D2_ + n]       = y1[c][r];
            res[(size_t)m * D2_ + 128 + n] = y2[c][r];
            xn[(size_t)m * D2_ + n]       = (_Float16)((y1[c][r] - mean) * inv * lnf_g[n] + lnf_b[n]);
            xn[(size_t)m * D2_ + 128 + n] = (_Float16)((y2[c][r] - mean) * inv * lnf_g[128 + n] + lnf_b[128 + n]);
        }
    }
}

// h = gelu(xn @ Wf1 + bf1)  [M x 512]
__global__ __launch_bounds__(256) void ffn1_kernel(const _Float16* xn, const _Float16* wsw,
        const float* bf1, _Float16* h) {
    int wave = threadIdx.x >> 6, lane = threadIdx.x & 63;
    int quad = lane >> 4, ln = lane & 15;
    int mbase = blockIdx.x * 64 + wave * 16;
    int nt = blockIdx.y;   // 0..3
    const _Float16* W = wsw + WF1_OFF;   // K=256, N=512, nc=32

    half8 a[8];
    const _Float16* Ar = xn + (size_t)(mbase + ln) * D2_ + quad * 8;
    #pragma unroll
    for (int s = 0; s < 8; s++) a[s] = *(const half8*)(Ar + s * 32);

    f32x4 acc[8];
    #pragma unroll
    for (int c = 0; c < 8; c++) {
        acc[c] = f32x4{0,0,0,0};
        int cg = nt * 8 + c;
        #pragma unroll
        for (int s = 0; s < 8; s++)
            acc[c] = mfma16(a[s], *(const half8*)(W + ((size_t)((s * 32 + cg) * 64 + lane)) * 8), acc[c]);
    }
    #pragma unroll
    for (int c = 0; c < 8; c++) {
        int n = nt * 128 + c * 16 + ln;
        float bv = bf1[n];
        #pragma unroll
        for (int r = 0; r < 4; r++) {
            float v = acc[c][r] + bv;
            float ge = 0.5f * v * (1.f + erff(v * 0.70710678118654752f));
            h[(size_t)(mbase + quad * 4 + r) * H_ + n] = (_Float16)ge;
        }
    }
}

// x = LN3(h @ Wf2 + bf2 + res) -> xn2 (fp16)
__global__ __launch_bounds__(256) void ffn2_kernel(const _Float16* h, const _Float16* wsw,
        const float* bf2, const float* res, const float* g3, const float* b3, _Float16* xn2) {
    int wave = threadIdx.x >> 6, lane = threadIdx.x & 63;
    int quad = lane >> 4, ln = lane & 15;
    int mbase = blockIdx.x * 64 + wave * 16;
    const _Float16* W = wsw + WF2_OFF;   // K=512, N=256, nc=16

    f32x4 acc[16];
    #pragma unroll
    for (int c = 0; c < 16; c++) acc[c] = f32x4{0,0,0,0};
    const _Float16* Ar = h + (size_t)(mbase + ln) * H_ + quad * 8;
    for (int s = 0; s < 16; s++) {
        half8 a = *(const half8*)(Ar + s * 32);
        #pragma unroll
        for (int c = 0; c < 16; c++)
            acc[c] = mfma16(a, *(const half8*)(W + ((size_t)((s * 16 + c) * 64 + lane)) * 8), acc[c]);
    }
    float sum[4] = {0,0,0,0}, sq[4] = {0,0,0,0};
    #pragma unroll
    for (int c = 0; c < 16; c++) {
        int n = c * 16 + ln;
        float bv = bf2[n];
        #pragma unroll
        for (int r = 0; r < 4; r++) {
            int m = mbase + quad * 4 + r;
            float v = acc[c][r] + bv + res[(size_t)m * D2_ + n];
            acc[c][r] = v; sum[r] += v; sq[r] += v * v;
        }
    }
    #pragma unroll
    for (int off = 1; off < 16; off <<= 1)
        #pragma unroll
        for (int r = 0; r < 4; r++) { sum[r] += __shfl_xor(sum[r], off); sq[r] += __shfl_xor(sq[r], off); }
    #pragma unroll
    for (int r = 0; r < 4; r++) {
        float mean = sum[r] * (1.f / 256.f);
        float var = sq[r] * (1.f / 256.f) - mean * mean;
        float inv = rsqrtf(var + 1e-5f);
        int m = mbase + quad * 4 + r;
        #pragma unroll
        for (int c = 0; c < 16; c++) {
            int n = c * 16 + ln;
            xn2[(size_t)m * D2_ + n] = (_Float16)((acc[c][r] - mean) * inv * g3[n] + b3[n]);
        }
    }
}

// out = xn2 @ Wo + bo   [M x 55] fp32
__global__ __launch_bounds__(256) void out_kernel(const _Float16* xn2, const _Float16* wsw,
        const float* bo, float* out) {
    int wave = threadIdx.x >> 6, lane = threadIdx.x & 63;
    int quad = lane >> 4, ln = lane & 15;
    int mbase = blockIdx.x * 64 + wave * 16;
    const _Float16* W = wsw + WO_OFF;   // K=256, N=64(padded), nc=4

    half8 a[8];
    const _Float16* Ar = xn2 + (size_t)(mbase + ln) * D2_ + quad * 8;
    #pragma unroll
    for (int s = 0; s < 8; s++) a[s] = *(const half8*)(Ar + s * 32);

    f32x4 acc[4];
    #pragma unroll
    for (int c = 0; c < 4; c++) {
        acc[c] = f32x4{0,0,0,0};
        #pragma unroll
        for (int s = 0; s < 8; s++)
            acc[c] = mfma16(a[s], *(const half8*)(W + ((size_t)((s * 4 + c) * 64 + lane)) * 8), acc[c]);
    }
    #pragma unroll
    for (int c = 0; c < 4; c++) {
        int n = c * 16 + ln;
        if (n < OUT_) {
            float bv = bo[n];
            #pragma unroll
            for (int r = 0; r < 4; r++)
                out[(size_t)(mbase + quad * 4 + r) * OUT_ + n] = acc[c][r] + bv;
        }
    }
}

extern "C" void kernel_launch(void* const* d_in, const int* in_sizes, int n_in,
                              void* d_out, int out_size, void* d_ws, size_t ws_size,
                              hipStream_t stream) {
    const float* x1    = (const float*)d_in[0];
    const float* x2    = (const float*)d_in[1];
    const float* ln1_g = (const float*)d_in[2];
    const float* ln1_b = (const float*)d_in[3];
    const float* ln2_g = (const float*)d_in[4];
    const float* ln2_b = (const float*)d_in[5];
    const float* Wq    = (const float*)d_in[6];
    const float* bq    = (const float*)d_in[7];
    const float* Wv1   = (const float*)d_in[8];
    const float* bv1   = (const float*)d_in[9];
    const float* Wk    = (const float*)d_in[10];
    const float* bk    = (const float*)d_in[11];
    const float* Wv2   = (const float*)d_in[12];
    const float* bv2   = (const float*)d_in[13];
    const float* Wp1   = (const float*)d_in[14];
    const float* bp1   = (const float*)d_in[15];
    const float* Wp2   = (const float*)d_in[16];
    const float* bp2   = (const float*)d_in[17];
    const float* lnf_g = (const float*)d_in[18];
    const float* lnf_b = (const float*)d_in[19];
    const float* Wf1   = (const float*)d_in[20];
    const float* bf1   = (const float*)d_in[21];
    const float* Wf2   = (const float*)d_in[22];
    const float* bf2   = (const float*)d_in[23];
    const float* ln3_g = (const float*)d_in[24];
    const float* ln3_b = (const float*)d_in[25];
    const float* Wo    = (const float*)d_in[26];
    const float* bo    = (const float*)d_in[27];
    float* out = (float*)d_out;

    char* ws = (char*)d_ws;
    const size_t MB = 1 << 20;
    _Float16* x1n  = (_Float16*)(ws + 0 * MB);
    _Float16* x2n  = (_Float16*)(ws + 4 * MB);
    _Float16* q1   = (_Float16*)(ws + 8 * MB);
    _Float16* k2   = (_Float16*)(ws + 12 * MB);
    _Float16* v1sw = (_Float16*)(ws + 16 * MB);
    _Float16* v2sw = (_Float16*)(ws + 20 * MB);
    _Float16* att1 = (_Float16*)(ws + 24 * MB);
    _Float16* att2 = (_Float16*)(ws + 28 * MB);
    float*    res  = (float*)   (ws + 32 * MB);   // 16 MB
    _Float16* xn   = (_Float16*)(ws + 48 * MB);   // 8 MB
    _Float16* h    = (_Float16*)(ws + 56 * MB);   // 16 MB
    _Float16* xn2  = (_Float16*)(ws + 72 * MB);   // 8 MB
    _Float16* wsw  = (_Float16*)(ws + 80 * MB);   // ~0.74 MB

    prep_kernel<<<dim3(512, 9), 256, 0, stream>>>(Wq, Wv1, Wk, Wv2, Wp1, Wp2, Wf1, Wf2, Wo, wsw);
    ln_kernel<<<dim3(M_ / 4, 2), 256, 0, stream>>>(x1, x2, ln1_g, ln1_b, ln2_g, ln2_b, x1n, x2n);
    proj_kernel<<<dim3(M_ / 64, 4), 256, 0, stream>>>(x1n, x2n, wsw, bq, bv1, bk, bv2,
                                                      q1, k2, v1sw, v2sw);
    flash_kernel<<<dim3(L_ / 64, B_), 256, 0, stream>>>(q1, k2, v1sw, v2sw, att1, att2);
    attn_out_kernel<<<dim3(M_ / 64), 256, 0, stream>>>(att1, att2, wsw, bp1, bp2,
                                                       x1, x2, lnf_g, lnf_b, res, xn);
    ffn1_kernel<<<dim3(M_ / 64, 4), 256, 0, stream>>>(xn, wsw, bf1, h);
    ffn2_kernel<<<dim3(M_ / 64), 256, 0, stream>>>(h, wsw, bf2, res, ln3_g, ln3_b, xn2);
    out_kernel<<<dim3(M_ / 64), 256, 0, stream>>>(xn2, wsw, bo, out);
}